// Round 1
// baseline (1308.401 us; speedup 1.0000x reference)
//
#include <hip/hip_runtime.h>

// MultiMarginLoss forward, p=1, margin=1.0, mean reduction.
// input: [B, C] fp32; target: [B] int; out: scalar fp32.
//
// loss_row = sum_{j != t} max(0, 1 - (x[t] - x[j]))
//          = (sum_{all j} max(0, (1 - x[t]) + x[j])) - 1.0   // target term == 1.0 exactly
// out = mean over rows.

__global__ void mml_zero_kernel(float* out) {
    out[0] = 0.0f;
}

__global__ __launch_bounds__(256) void mml_kernel(const float* __restrict__ input,
                                                  const int* __restrict__ target,
                                                  float* __restrict__ out,
                                                  int C, float inv_B) {
    const int row = blockIdx.x;
    const float* rowp = input + (size_t)row * (size_t)C;

    __shared__ float s_correct;
    if (threadIdx.x == 0) {
        int t = target[row];
        s_correct = rowp[t];
    }
    __syncthreads();

    const float thresh = 1.0f - s_correct;  // hinge_j = max(0, thresh + x_j)

    float acc = 0.0f;
    const int n4 = C >> 2;  // C = 32000 -> 8000 float4s
    const float4* __restrict__ rp4 = (const float4*)rowp;
    for (int i = threadIdx.x; i < n4; i += 256) {
        float4 v = rp4[i];
        acc += fmaxf(0.0f, thresh + v.x);
        acc += fmaxf(0.0f, thresh + v.y);
        acc += fmaxf(0.0f, thresh + v.z);
        acc += fmaxf(0.0f, thresh + v.w);
    }
    // tail (empty for C % 4 == 0, kept for generality)
    for (int i = (n4 << 2) + threadIdx.x; i < C; i += 256) {
        acc += fmaxf(0.0f, thresh + rowp[i]);
    }

    // wave (64-lane) shuffle reduction
    #pragma unroll
    for (int off = 32; off > 0; off >>= 1)
        acc += __shfl_down(acc, off, 64);

    __shared__ float s_part[4];
    const int lane = threadIdx.x & 63;
    const int wave = threadIdx.x >> 6;
    if (lane == 0) s_part[wave] = acc;
    __syncthreads();

    if (threadIdx.x == 0) {
        float tot = s_part[0] + s_part[1] + s_part[2] + s_part[3];
        tot -= 1.0f;                 // remove the target-column hinge (== margin == 1.0)
        atomicAdd(out, tot * inv_B); // 8192 atomics to one address: negligible
    }
}

extern "C" void kernel_launch(void* const* d_in, const int* in_sizes, int n_in,
                              void* d_out, int out_size, void* d_ws, size_t ws_size,
                              hipStream_t stream) {
    const float* input = (const float*)d_in[0];
    const int* target = (const int*)d_in[1];
    float* out = (float*)d_out;

    const int B = in_sizes[1];               // 8192
    const int C = in_sizes[0] / in_sizes[1]; // 32000

    // d_out is poisoned to 0xAA before each timed launch -> zero it first.
    mml_zero_kernel<<<1, 1, 0, stream>>>(out);
    mml_kernel<<<B, 256, 0, stream>>>(input, target, out, C, 1.0f / (float)B);
}

// Round 2
// 1293.217 us; speedup vs baseline: 1.0117x; 1.0117x over previous
//
#include <hip/hip_runtime.h>

// MultiMarginLoss forward, p=1, margin=1.0, mean reduction.
// input: [B, C] fp32; target: [B] int; out: scalar fp32.
//
// loss_row = sum_{j != t} max(0, 1 - (x[t] - x[j]))
//          = (sum_{all j} max(0, (1 - x[t]) + x[j])) - 1.0   // target term == 1.0 exactly
// out = mean over rows.
//
// Two-phase: (A) gather thresh[row] = 1 - x[row, t_row] into ws + zero out;
// (B) persistent blocks stream the matrix, 8 rows/block, one atomic/block.

#define ROWS_PER_BLOCK 8
#define BLOCK 256

__global__ __launch_bounds__(BLOCK) void mml_gather_kernel(const float* __restrict__ input,
                                                           const int* __restrict__ target,
                                                           float* __restrict__ thresh,
                                                           float* __restrict__ out,
                                                           int B, int C) {
    int row = blockIdx.x * BLOCK + threadIdx.x;
    if (row < B) {
        int t = target[row];
        thresh[row] = 1.0f - input[(size_t)row * (size_t)C + t];
    }
    if (row == 0) out[0] = 0.0f;
}

__global__ __launch_bounds__(BLOCK) void mml_main_kernel(const float* __restrict__ input,
                                                         const float* __restrict__ thresh,
                                                         float* __restrict__ out,
                                                         int B, int C, float inv_B) {
    const int r0 = blockIdx.x * ROWS_PER_BLOCK;
    const int r1 = (r0 + ROWS_PER_BLOCK < B) ? r0 + ROWS_PER_BLOCK : B;
    const int n4 = C >> 2;

    float acc = 0.0f;  // per-thread partial across ALL rows of this block

    for (int row = r0; row < r1; ++row) {
        const float th = thresh[row];  // same address for all 256 threads: broadcast, L1/L2 hit
        const float4* __restrict__ rp4 = (const float4*)(input + (size_t)row * (size_t)C);
        for (int i = threadIdx.x; i < n4; i += BLOCK) {
            float4 v = rp4[i];
            acc += fmaxf(0.0f, th + v.x);
            acc += fmaxf(0.0f, th + v.y);
            acc += fmaxf(0.0f, th + v.z);
            acc += fmaxf(0.0f, th + v.w);
        }
        // tail for C % 4 != 0 (empty for C = 32000)
        const float* rowp = input + (size_t)row * (size_t)C;
        for (int i = (n4 << 2) + threadIdx.x; i < C; i += BLOCK) {
            acc += fmaxf(0.0f, th + rowp[i]);
        }
    }

    // single block-level reduction at the very end
    #pragma unroll
    for (int off = 32; off > 0; off >>= 1)
        acc += __shfl_down(acc, off, 64);

    __shared__ float s_part[BLOCK / 64];
    const int lane = threadIdx.x & 63;
    const int wave = threadIdx.x >> 6;
    if (lane == 0) s_part[wave] = acc;
    __syncthreads();

    if (threadIdx.x == 0) {
        float tot = 0.0f;
        #pragma unroll
        for (int w = 0; w < BLOCK / 64; ++w) tot += s_part[w];
        tot -= (float)(r1 - r0);      // remove target-column hinge (== 1.0) per row
        atomicAdd(out, tot * inv_B);  // 1024 atomics to one address
    }
}

extern "C" void kernel_launch(void* const* d_in, const int* in_sizes, int n_in,
                              void* d_out, int out_size, void* d_ws, size_t ws_size,
                              hipStream_t stream) {
    const float* input = (const float*)d_in[0];
    const int* target = (const int*)d_in[1];
    float* out = (float*)d_out;
    float* thresh = (float*)d_ws;  // B floats of scratch

    const int B = in_sizes[1];               // 8192
    const int C = in_sizes[0] / in_sizes[1]; // 32000

    mml_gather_kernel<<<(B + BLOCK - 1) / BLOCK, BLOCK, 0, stream>>>(input, target, thresh, out, B, C);

    const int grid = (B + ROWS_PER_BLOCK - 1) / ROWS_PER_BLOCK;  // 1024
    mml_main_kernel<<<grid, BLOCK, 0, stream>>>(input, thresh, out, B, C, 1.0f / (float)B);
}